// Round 9
// baseline (294.306 us; speedup 1.0000x reference)
//
#include <hip/hip_runtime.h>
#include <hip/hip_bf16.h>
#include <math.h>

#define L 2048
#define D 256

typedef __attribute__((ext_vector_type(8))) short bf16x8;
typedef __attribute__((ext_vector_type(4))) float f32x4;
typedef __attribute__((ext_vector_type(4))) int i32x4;

__device__ __forceinline__ unsigned short f2bf(float f) {
    union { float f; unsigned int u; } v; v.f = f;
    unsigned int r = v.u + 0x7FFFu + ((v.u >> 16) & 1u);   // RNE
    return (unsigned short)(r >> 16);
}

// --- prep: fused {Wv transpose -> LDS} + {value @ Wv + bv -> Vt bf16}
//     + side-job {Wo transpose -> Wot global}
__global__ __launch_bounds__(256, 4) void prep_kernel(
    const float* __restrict__ value, const float* __restrict__ Wv,
    const float* __restrict__ bv, const float* __restrict__ Wo,
    unsigned short* __restrict__ Vt, unsigned short* __restrict__ Wot) {
    const int tid = threadIdx.x;
    const int wave = tid >> 6, lane = tid & 63;
    const int lm = lane & 15, q = lane >> 4;
    const int rh = wave >> 1;
    const int nh = wave & 1;
    const int m0 = blockIdx.x * 32;
    const int n0 = blockIdx.y * 64;

    __shared__ __align__(16) unsigned short Wlds[64][264];

    {
        int bid = blockIdx.y * 256 + blockIdx.x;
        if (tid < 64) {
            int e = bid * 64 + tid;
            int k = e >> 8, n = e & 255;
            Wot[n * 256 + k] = f2bf(Wo[k * 256 + n]);
        }
    }
    {
        int krow = tid >> 4;
        int nrel = (tid & 15) * 4;
#pragma unroll
        for (int p = 0; p < 16; p++) {
            int k = p * 16 + krow;
            f32x4 w = *reinterpret_cast<const f32x4*>(Wv + (size_t)k * 256 + n0 + nrel);
            Wlds[nrel + 0][k] = f2bf(w[0]);
            Wlds[nrel + 1][k] = f2bf(w[1]);
            Wlds[nrel + 2][k] = f2bf(w[2]);
            Wlds[nrel + 3][k] = f2bf(w[3]);
        }
    }
    __syncthreads();

    const int nl0 = nh * 32 + lm;
    const int nl1 = nh * 32 + 16 + lm;
    const int arow = m0 + rh * 16 + lm;

    f32x4 acc[2];
    acc[0] = (f32x4)(0.f); acc[1] = (f32x4)(0.f);

    const float* ap = value + (size_t)arow * 256;
    f32x4 pa0 = *reinterpret_cast<const f32x4*>(ap + q * 8);
    f32x4 pa1 = *reinterpret_cast<const f32x4*>(ap + q * 8 + 4);

    for (int k0 = 0; k0 < 256; k0 += 32) {
        f32x4 a0 = pa0, a1 = pa1;
        if (k0 < 224) {
            int kq = k0 + 32 + q * 8;
            pa0 = *reinterpret_cast<const f32x4*>(ap + kq);
            pa1 = *reinterpret_cast<const f32x4*>(ap + kq + 4);
        }
        bf16x8 b0 = *reinterpret_cast<const bf16x8*>(&Wlds[nl0][k0 + q * 8]);
        bf16x8 b1 = *reinterpret_cast<const bf16x8*>(&Wlds[nl1][k0 + q * 8]);
        bf16x8 afr;
#pragma unroll
        for (int e = 0; e < 4; e++) afr[e] = (short)f2bf(a0[e]);
#pragma unroll
        for (int e = 0; e < 4; e++) afr[4 + e] = (short)f2bf(a1[e]);
        acc[0] = __builtin_amdgcn_mfma_f32_16x16x32_bf16(afr, b0, acc[0], 0, 0, 0);
        acc[1] = __builtin_amdgcn_mfma_f32_16x16x32_bf16(afr, b1, acc[1], 0, 0, 0);
    }

    int mrow = m0 + rh * 16 + q * 4;
    int b = mrow >> 11;
    int j = mrow & 2047;
#pragma unroll
    for (int nf = 0; nf < 2; nf++) {
        int n = n0 + nh * 32 + nf * 16 + lm;
        float bias_n = bv[n];
        const f32x4& a = acc[nf];
        unsigned short* dst = Vt + (size_t)b * (D * L) + (size_t)n * L + j;
        ushort4 pk;
        pk.x = f2bf(a[0] + bias_n);
        pk.y = f2bf(a[1] + bias_n);
        pk.z = f2bf(a[2] + bias_n);
        pk.w = f2bf(a[3] + bias_n);
        *reinterpret_cast<ushort4*>(dst) = pk;
    }
}

// --- attn: TWO BARRIER-FREE PHASES inside one block ---------------------
// Block = 16 rows x all 2048 j. 512 blocks x 256 thr, 2 blocks/CU
// (LDS-limited: P-tile 64KB in LDS).
// Phase A (streaming): P[16][2048] = masked-exp(logits) -> LDS, with
//   perfectly coalesced loads (per instr: 4 rows x 256B fully consumed),
//   96 independent loads/thread, NO barriers. l accumulated in registers.
// ONE __syncthreads.
// Phase B (GEMM): O = P @ V, 64 iters x {1 ds_read + 4 Vt loads + 4 MFMA},
//   NO barriers (P-tile is read-only now) -> compiler register-pipelines.
// Epilogue: /l, bf16 -> A_lds, @ Wo + bo -> out (proven r4 code).
// P never touches HBM; traffic = mandatory 192MB logits + 8MB out.
__global__ __launch_bounds__(256, 2) void attn_kernel(
    const float* __restrict__ atten, const float* __restrict__ mask,
    const int* __restrict__ pad, const unsigned short* __restrict__ Vt,
    const unsigned short* __restrict__ Wot, const float* __restrict__ bo,
    float* __restrict__ out) {
    const int bid = blockIdx.x;        // 0..511
    const int g = (bid & 7) * 64 + (bid >> 3);   // XCD-chunked: 1 batch-half/XCD
    const int b = g >> 7;
    const int i0 = (g & 127) * 16;
    const int tid = threadIdx.x;
    const int wave = tid >> 6, lane = tid & 63;
    const int lm = lane & 15, q = lane >> 4;

    // stride 2056 ushorts = 4112B: 16B-aligned rows (ds_read_b128 legal)
    __shared__ __align__(16) unsigned short Plds[16][2056];
    __shared__ __align__(16) unsigned short A_lds[16][264];
    __shared__ float l_lds[16];

    // ---------------- phase A: streaming masked-exp -> Plds -------------
    {
        const int r = tid >> 4;            // row 0..15
        const int c4 = (tid & 15) * 4;     // j sub-offset
        const size_t rowbase = ((size_t)(b * L + i0 + r)) * L + c4;
        const float* at_r = atten + rowbase;
        const float* mk_r = mask + rowbase;
        const int*   pd_r = pad + rowbase;
        float lsum = 0.f;
#pragma unroll 2
        for (int jt = 0; jt < 8; jt++) {
            const int jb = jt * 256;
            f32x4 av[4], mv[4];
            i32x4 pv[4];
#pragma unroll
            for (int s = 0; s < 4; s++) {
                av[s] = *reinterpret_cast<const f32x4*>(at_r + jb + s * 64);
                mv[s] = *reinterpret_cast<const f32x4*>(mk_r + jb + s * 64);
                pv[s] = *reinterpret_cast<const i32x4*>(pd_r + jb + s * 64);
            }
#pragma unroll
            for (int s = 0; s < 4; s++) {
                float pe[4];
#pragma unroll
                for (int e = 0; e < 4; e++) {
                    float p = __expf(av[s][e]);        // exp first (finite input)
                    p = (mv[s][e] < 0.5f) ? 0.f : p;   // masked -> exactly 0
                    p = (pv[s][e] == 0) ? 0.f : p;     // (== exp(-inf/-FLT_MAX))
                    pe[e] = p;
                }
                lsum += (pe[0] + pe[1]) + (pe[2] + pe[3]);
                ushort4 pk;
                pk.x = f2bf(pe[0]); pk.y = f2bf(pe[1]);
                pk.z = f2bf(pe[2]); pk.w = f2bf(pe[3]);
                *reinterpret_cast<ushort4*>(&Plds[r][jb + c4 + s * 64]) = pk;
            }
        }
        // l-reduction: 16 consecutive lanes share row r (same wave)
        lsum += __shfl_xor(lsum, 1);
        lsum += __shfl_xor(lsum, 2);
        lsum += __shfl_xor(lsum, 4);
        lsum += __shfl_xor(lsum, 8);
        if ((tid & 15) == 0) l_lds[r] = lsum;
    }
    __syncthreads();     // the ONLY main sync: publishes Plds + l_lds

    // ---------------- phase B: O = P @ V, barrier-free ------------------
    f32x4 acc[4];
#pragma unroll
    for (int nf = 0; nf < 4; nf++) acc[nf] = (f32x4)(0.f);

    const unsigned short* vt_b = Vt + (size_t)b * (D * L) + q * 8;
    const unsigned short* prow = &Plds[lm][q * 8];
#pragma unroll 2
    for (int j0 = 0; j0 < 2048; j0 += 32) {
        bf16x8 afr = *reinterpret_cast<const bf16x8*>(prow + j0);
#pragma unroll
        for (int nf = 0; nf < 4; nf++) {
            int n = wave * 64 + nf * 16 + lm;
            bf16x8 bfr = *reinterpret_cast<const bf16x8*>(vt_b + (size_t)n * L + j0);
            acc[nf] = __builtin_amdgcn_mfma_f32_16x16x32_bf16(
                afr, bfr, acc[nf], 0, 0, 0);
        }
    }

    // normalize, pack bf16 A for the out-projection
    float linv[4];
#pragma unroll
    for (int rg = 0; rg < 4; rg++) linv[rg] = 1.f / l_lds[q * 4 + rg];
#pragma unroll
    for (int nf = 0; nf < 4; nf++) {
        int n = wave * 64 + nf * 16 + lm;
#pragma unroll
        for (int rg = 0; rg < 4; rg++)
            A_lds[q * 4 + rg][n] = f2bf(acc[nf][rg] * linv[rg]);
    }
    __syncthreads();

    // out-projection: [16][256] @ Wo + bo, each wave 64 n
    f32x4 oacc[4];
#pragma unroll
    for (int nf = 0; nf < 4; nf++) oacc[nf] = (f32x4)(0.f);
    for (int k0 = 0; k0 < 256; k0 += 32) {
        bf16x8 afr = *reinterpret_cast<const bf16x8*>(&A_lds[lm][k0 + q * 8]);
#pragma unroll
        for (int nf = 0; nf < 4; nf++) {
            int n = wave * 64 + nf * 16 + lm;
            bf16x8 bfrW = *reinterpret_cast<const bf16x8*>(
                Wot + (size_t)n * 256 + k0 + q * 8);
            oacc[nf] = __builtin_amdgcn_mfma_f32_16x16x32_bf16(
                afr, bfrW, oacc[nf], 0, 0, 0);
        }
    }
#pragma unroll
    for (int nf = 0; nf < 4; nf++) {
        int n = wave * 64 + nf * 16 + lm;
        float bias_n = bo[n];
#pragma unroll
        for (int rg = 0; rg < 4; rg++)
            out[((size_t)(b * L + i0 + q * 4 + rg)) * 256 + n] = oacc[nf][rg] + bias_n;
    }
}

extern "C" void kernel_launch(void* const* d_in, const int* in_sizes, int n_in,
                              void* d_out, int out_size, void* d_ws, size_t ws_size,
                              hipStream_t stream) {
    (void)in_sizes; (void)n_in; (void)out_size; (void)ws_size;
    const float* atten = (const float*)d_in[0];
    const float* value = (const float*)d_in[1];
    const float* mask  = (const float*)d_in[2];
    const int*   pad   = (const int*)d_in[3];
    const float* Wv    = (const float*)d_in[4];
    const float* bv    = (const float*)d_in[5];
    const float* Wo    = (const float*)d_in[6];
    const float* bo    = (const float*)d_in[7];
    float* out = (float*)d_out;

    char* ws = (char*)d_ws;
    unsigned short* Vt  = (unsigned short*)(ws);              // 4 MB  bf16 [B][D][L]
    unsigned short* Wot = (unsigned short*)(ws + 4194304);    // 128 KB

    prep_kernel<<<dim3(256, 4), 256, 0, stream>>>(value, Wv, bv, Wo, Vt, Wot);
    attn_kernel<<<512, 256, 0, stream>>>(atten, mask, pad, Vt, Wot, bo, out);
}

// Round 10
// 290.455 us; speedup vs baseline: 1.0133x; 1.0133x over previous
//
#include <hip/hip_runtime.h>
#include <hip/hip_bf16.h>
#include <math.h>

#define L 2048
#define D 256

typedef __attribute__((ext_vector_type(8))) short bf16x8;
typedef __attribute__((ext_vector_type(4))) float f32x4;
typedef __attribute__((ext_vector_type(4))) int i32x4;

__device__ __forceinline__ unsigned short f2bf(float f) {
    union { float f; unsigned int u; } v; v.f = f;
    unsigned int r = v.u + 0x7FFFu + ((v.u >> 16) & 1u);   // RNE
    return (unsigned short)(r >> 16);
}

// --- prep: fused {Wv transpose -> LDS} + {value @ Wv + bv -> Vt bf16}
//     + side-job {Wo transpose -> Wot global}   (proven r4 kernel)
__global__ __launch_bounds__(256, 4) void prep_kernel(
    const float* __restrict__ value, const float* __restrict__ Wv,
    const float* __restrict__ bv, const float* __restrict__ Wo,
    unsigned short* __restrict__ Vt, unsigned short* __restrict__ Wot) {
    const int tid = threadIdx.x;
    const int wave = tid >> 6, lane = tid & 63;
    const int lm = lane & 15, q = lane >> 4;
    const int rh = wave >> 1;
    const int nh = wave & 1;
    const int m0 = blockIdx.x * 32;
    const int n0 = blockIdx.y * 64;

    __shared__ __align__(16) unsigned short Wlds[64][264];

    {
        int bid = blockIdx.y * 256 + blockIdx.x;
        if (tid < 64) {
            int e = bid * 64 + tid;
            int k = e >> 8, n = e & 255;
            Wot[n * 256 + k] = f2bf(Wo[k * 256 + n]);
        }
    }
    {
        int krow = tid >> 4;
        int nrel = (tid & 15) * 4;
#pragma unroll
        for (int p = 0; p < 16; p++) {
            int k = p * 16 + krow;
            f32x4 w = *reinterpret_cast<const f32x4*>(Wv + (size_t)k * 256 + n0 + nrel);
            Wlds[nrel + 0][k] = f2bf(w[0]);
            Wlds[nrel + 1][k] = f2bf(w[1]);
            Wlds[nrel + 2][k] = f2bf(w[2]);
            Wlds[nrel + 3][k] = f2bf(w[3]);
        }
    }
    __syncthreads();

    const int nl0 = nh * 32 + lm;
    const int nl1 = nh * 32 + 16 + lm;
    const int arow = m0 + rh * 16 + lm;

    f32x4 acc[2];
    acc[0] = (f32x4)(0.f); acc[1] = (f32x4)(0.f);

    const float* ap = value + (size_t)arow * 256;
    f32x4 pa0 = *reinterpret_cast<const f32x4*>(ap + q * 8);
    f32x4 pa1 = *reinterpret_cast<const f32x4*>(ap + q * 8 + 4);

    for (int k0 = 0; k0 < 256; k0 += 32) {
        f32x4 a0 = pa0, a1 = pa1;
        if (k0 < 224) {
            int kq = k0 + 32 + q * 8;
            pa0 = *reinterpret_cast<const f32x4*>(ap + kq);
            pa1 = *reinterpret_cast<const f32x4*>(ap + kq + 4);
        }
        bf16x8 b0 = *reinterpret_cast<const bf16x8*>(&Wlds[nl0][k0 + q * 8]);
        bf16x8 b1 = *reinterpret_cast<const bf16x8*>(&Wlds[nl1][k0 + q * 8]);
        bf16x8 afr;
#pragma unroll
        for (int e = 0; e < 4; e++) afr[e] = (short)f2bf(a0[e]);
#pragma unroll
        for (int e = 0; e < 4; e++) afr[4 + e] = (short)f2bf(a1[e]);
        acc[0] = __builtin_amdgcn_mfma_f32_16x16x32_bf16(afr, b0, acc[0], 0, 0, 0);
        acc[1] = __builtin_amdgcn_mfma_f32_16x16x32_bf16(afr, b1, acc[1], 0, 0, 0);
    }

    int mrow = m0 + rh * 16 + q * 4;
    int b = mrow >> 11;
    int j = mrow & 2047;
#pragma unroll
    for (int nf = 0; nf < 2; nf++) {
        int n = n0 + nh * 32 + nf * 16 + lm;
        float bias_n = bv[n];
        const f32x4& a = acc[nf];
        unsigned short* dst = Vt + (size_t)b * (D * L) + (size_t)n * L + j;
        ushort4 pk;
        pk.x = f2bf(a[0] + bias_n);
        pk.y = f2bf(a[1] + bias_n);
        pk.z = f2bf(a[2] + bias_n);
        pk.w = f2bf(a[3] + bias_n);
        *reinterpret_cast<ushort4*>(dst) = pk;
    }
}

// --- attn: barrier-free two-phase AT 16 WAVES/CU ------------------------
// 1024 blocks (b, js, 16-row group) x 256 thr, launch_bounds(256,4)
// -> 4 blocks/CU = 16 waves/CU (the only lever that ever raised BW).
// Phase A: P[16][1024] = masked-exp(logits) -> 33KB LDS tile. Pure
//   streaming, perfectly coalesced, ZERO in-loop barriers.
// ONE __syncthreads.
// Phase B: partial = P @ V from LDS + L2-resident Vt, barrier-free.
// Partials (16KB f32/block) combine by plain addition in gemm_out
// (no-max softmax => additive) -- proven cheap in r8.
__global__ __launch_bounds__(256, 4) void attn_kernel(
    const float* __restrict__ atten, const float* __restrict__ mask,
    const int* __restrict__ pad, const unsigned short* __restrict__ Vt,
    float* __restrict__ part) {
    const int bid = blockIdx.x;                  // 0..1023
    const int g = (bid & 7) * 128 + (bid >> 3);  // XCD-chunked: one (b,js)/XCD
    const int b = g >> 8;
    const int js = (g >> 7) & 1;
    const int i0 = (g & 127) * 16;
    const int tid = threadIdx.x;
    const int wave = tid >> 6, lane = tid & 63;
    const int lm = lane & 15, q = lane >> 4;

    // stride 1032 ushorts = 2064B (16B multiple -> ds_read_b128 legal)
    __shared__ __align__(16) unsigned short Plds[16][1032];

    float* pbase = part + (size_t)g * 4112;

    // ---------------- phase A: streaming masked-exp -> Plds -------------
    {
        const int r = tid >> 4;            // row 0..15
        const int c4 = (tid & 15) * 4;     // j sub-offset (consecutive j!)
        const size_t rowbase = ((size_t)(b * L + i0 + r)) * L + js * 1024 + c4;
        const float* at_r = atten + rowbase;
        const float* mk_r = mask + rowbase;
        const int*   pd_r = pad + rowbase;
        float lsum = 0.f;
#pragma unroll 2
        for (int jt = 0; jt < 16; jt++) {
            const int jb = jt * 64;
            f32x4 av = *reinterpret_cast<const f32x4*>(at_r + jb);
            f32x4 mv = *reinterpret_cast<const f32x4*>(mk_r + jb);
            i32x4 pv = *reinterpret_cast<const i32x4*>(pd_r + jb);
            float pe[4];
#pragma unroll
            for (int e = 0; e < 4; e++) {
                float p = __expf(av[e]);           // exp first (finite input)
                p = (mv[e] < 0.5f) ? 0.f : p;      // masked -> exactly 0
                p = (pv[e] == 0) ? 0.f : p;
                pe[e] = p;
            }
            lsum += (pe[0] + pe[1]) + (pe[2] + pe[3]);
            ushort4 pk;
            pk.x = f2bf(pe[0]); pk.y = f2bf(pe[1]);
            pk.z = f2bf(pe[2]); pk.w = f2bf(pe[3]);
            *reinterpret_cast<ushort4*>(&Plds[r][jb + c4]) = pk;
        }
        // l-reduction: 16 consecutive lanes share row r (same wave)
        lsum += __shfl_xor(lsum, 1);
        lsum += __shfl_xor(lsum, 2);
        lsum += __shfl_xor(lsum, 4);
        lsum += __shfl_xor(lsum, 8);
        if ((tid & 15) == 0) pbase[4096 + r] = lsum;   // straight to partial
    }
    __syncthreads();     // the ONLY sync: publishes Plds

    // ---------------- phase B: partial = P @ V, barrier-free ------------
    f32x4 acc[4];
#pragma unroll
    for (int nf = 0; nf < 4; nf++) acc[nf] = (f32x4)(0.f);

    const unsigned short* vt_b = Vt + (size_t)b * (D * L) + js * 1024 + q * 8;
    const unsigned short* prow = &Plds[lm][q * 8];
#pragma unroll 2
    for (int j0 = 0; j0 < 1024; j0 += 32) {
        bf16x8 afr = *reinterpret_cast<const bf16x8*>(prow + j0);
#pragma unroll
        for (int nf = 0; nf < 4; nf++) {
            int n = wave * 64 + nf * 16 + lm;
            bf16x8 bfr = *reinterpret_cast<const bf16x8*>(vt_b + (size_t)n * L + j0);
            acc[nf] = __builtin_amdgcn_mfma_f32_16x16x32_bf16(
                afr, bfr, acc[nf], 0, 0, 0);
        }
    }

    // store partial acc[16][256] f32
#pragma unroll
    for (int nf = 0; nf < 4; nf++) {
        int n = wave * 64 + nf * 16 + lm;
#pragma unroll
        for (int rg = 0; rg < 4; rg++)
            pbase[(q * 4 + rg) * 256 + n] = acc[nf][rg];
    }
}

// --- output GEMM with fused js-pair combine (plain addition, r8 proven) -
__global__ __launch_bounds__(256, 2) void gemm_out_kernel(
    const float* __restrict__ part,
    const unsigned short* __restrict__ Wt,
    const float* __restrict__ bias,
    float* __restrict__ Cout) {
    const int wave = threadIdx.x >> 6;
    const int lane = threadIdx.x & 63;
    const int lm = lane & 15, q = lane >> 4;
    const int m0 = blockIdx.x * 64;
    const int n0 = blockIdx.y * 64;
    const int arow = m0 + wave * 16 + lm;
    const int b = arow >> 11;
    const int rg16 = (arow & 2047) >> 4;
    const int r_in = arow & 15;
    const float* pb0 = part + (size_t)(b * 256 + rg16) * 4112;
    const float* pb1 = pb0 + (size_t)128 * 4112;

    float linv = 1.f / (pb0[4096 + r_in] + pb1[4096 + r_in]);

    int ncol[4];
#pragma unroll
    for (int nf = 0; nf < 4; nf++) ncol[nf] = n0 + nf * 16 + lm;

    f32x4 acc[4];
#pragma unroll
    for (int nf = 0; nf < 4; nf++) acc[nf] = (f32x4)(0.f);

    for (int k0 = 0; k0 < 256; k0 += 32) {
        int kq = k0 + q * 8;
        bf16x8 bfr[4];
#pragma unroll
        for (int nf = 0; nf < 4; nf++)
            bfr[nf] = *reinterpret_cast<const bf16x8*>(Wt + (size_t)ncol[nf] * 256 + kq);
        f32x4 s0 = *reinterpret_cast<const f32x4*>(pb0 + r_in * 256 + kq)
                 + *reinterpret_cast<const f32x4*>(pb1 + r_in * 256 + kq);
        f32x4 s1 = *reinterpret_cast<const f32x4*>(pb0 + r_in * 256 + kq + 4)
                 + *reinterpret_cast<const f32x4*>(pb1 + r_in * 256 + kq + 4);
        bf16x8 afr;
#pragma unroll
        for (int e = 0; e < 4; e++) afr[e] = (short)f2bf(s0[e] * linv);
#pragma unroll
        for (int e = 0; e < 4; e++) afr[4 + e] = (short)f2bf(s1[e] * linv);
#pragma unroll
        for (int nf = 0; nf < 4; nf++)
            acc[nf] = __builtin_amdgcn_mfma_f32_16x16x32_bf16(
                afr, bfr[nf], acc[nf], 0, 0, 0);
    }

    int mrow = m0 + wave * 16 + q * 4;
#pragma unroll
    for (int nf = 0; nf < 4; nf++) {
        int n = ncol[nf];
        float bias_n = bias[n];
#pragma unroll
        for (int rg = 0; rg < 4; rg++)
            Cout[(size_t)(mrow + rg) * 256 + n] = acc[nf][rg] + bias_n;
    }
}

extern "C" void kernel_launch(void* const* d_in, const int* in_sizes, int n_in,
                              void* d_out, int out_size, void* d_ws, size_t ws_size,
                              hipStream_t stream) {
    (void)in_sizes; (void)n_in; (void)out_size; (void)ws_size;
    const float* atten = (const float*)d_in[0];
    const float* value = (const float*)d_in[1];
    const float* mask  = (const float*)d_in[2];
    const int*   pad   = (const int*)d_in[3];
    const float* Wv    = (const float*)d_in[4];
    const float* bv    = (const float*)d_in[5];
    const float* Wo    = (const float*)d_in[6];
    const float* bo    = (const float*)d_in[7];
    float* out = (float*)d_out;

    char* ws = (char*)d_ws;
    unsigned short* Vt  = (unsigned short*)(ws);              // 4 MB  bf16 [B][D][L]
    unsigned short* Wot = (unsigned short*)(ws + 4194304);    // 128 KB
    float* part = (float*)(ws + 4325376);                     // 1024 * 16448 B = 16.8 MB

    prep_kernel<<<dim3(256, 4), 256, 0, stream>>>(value, Wv, bv, Wo, Vt, Wot);
    attn_kernel<<<1024, 256, 0, stream>>>(atten, mask, pad, Vt, part);
    gemm_out_kernel<<<dim3(128, 4), 256, 0, stream>>>(part, Wot, bo, out);
}